// Round 1
// baseline (822.045 us; speedup 1.0000x reference)
//
#include <hip/hip_runtime.h>
#include <cmath>
#include <stdint.h>

typedef unsigned short ushort_t;
typedef __attribute__((ext_vector_type(8))) short bf16x8;
typedef __attribute__((ext_vector_type(4))) float f32x4;

#define LOG2E 1.4426950408889634f

__device__ __forceinline__ float bf2f(unsigned short u) {
    return __uint_as_float(((unsigned)u) << 16);
}
__device__ __forceinline__ unsigned short f2bf(float f) {
    unsigned u = __float_as_uint(f);
    u = u + 0x7fffu + ((u >> 16) & 1u);
    return (unsigned short)(u >> 16);
}
__device__ __forceinline__ void gld_lds16(void* lds, const void* g) {
    __builtin_amdgcn_global_load_lds(
        (const __attribute__((address_space(1))) unsigned int*)g,
        (__attribute__((address_space(3))) unsigned int*)lds,
        16, 0, 0);
}

// ---------------------------------------------------------------- cast kernel
// x (8.4M f32) -> xb bf16; Wq,Wk,Wv -> wqkvb (concat rows, bf16); Wo -> wob;
// bq,bk,bv -> biasqkv (f32 concat).
__global__ __launch_bounds__(256) void cast_all(
    const float* __restrict__ x, const float* __restrict__ wq,
    const float* __restrict__ wk, const float* __restrict__ wv,
    const float* __restrict__ wo, const float* __restrict__ bq,
    const float* __restrict__ bk, const float* __restrict__ bv,
    ushort_t* __restrict__ xb, ushort_t* __restrict__ wqkvb,
    ushort_t* __restrict__ wob, float* __restrict__ biasqkv)
{
    const int X4 = 2097152;   // 8.4M / 4
    const int W4 = 1048576;   // 4.2M / 4
    int i = blockIdx.x * 256 + threadIdx.x;
    if (i < X4) {
        float4 v = ((const float4*)x)[i];
        ushort_t* d = xb + (size_t)i * 4;
        d[0]=f2bf(v.x); d[1]=f2bf(v.y); d[2]=f2bf(v.z); d[3]=f2bf(v.w);
    } else if (i < X4 + 3*W4) {
        int j = i - X4;
        const float* w; int jj;
        if (j < W4)        { w = wq; jj = j; }
        else if (j < 2*W4) { w = wk; jj = j - W4; }
        else               { w = wv; jj = j - 2*W4; }
        float4 v = ((const float4*)w)[jj];
        ushort_t* d = wqkvb + (size_t)j * 4;
        d[0]=f2bf(v.x); d[1]=f2bf(v.y); d[2]=f2bf(v.z); d[3]=f2bf(v.w);
    } else if (i < X4 + 4*W4) {
        int j = i - X4 - 3*W4;
        float4 v = ((const float4*)wo)[j];
        ushort_t* d = wob + (size_t)j * 4;
        d[0]=f2bf(v.x); d[1]=f2bf(v.y); d[2]=f2bf(v.z); d[3]=f2bf(v.w);
    } else {
        int j = i - X4 - 4*W4;           // 0..1535
        const float4* s;
        if (j < 512)       s = (const float4*)bq + j;
        else if (j < 1024) s = (const float4*)bk + (j - 512);
        else               s = (const float4*)bv + (j - 1024);
        ((float4*)biasqkv)[j] = *s;
    }
}

// ---------------------------------------------------------------- GEMM (B^T)
// C[M,N] = A[M,K] @ Bw[N,K]^T + bias[N].  128x128 tile, BK=64, 4 waves.
// OUTF32=0: bf16 out; OUTF32=1: f32 out.
template<int OUTF32>
__global__ __launch_bounds__(256, 2) void gemm_bt(
    const ushort_t* __restrict__ A, const ushort_t* __restrict__ Bw,
    const float* __restrict__ bias, void* __restrict__ Cout,
    int M, int N, int K)
{
    __shared__ __align__(16) ushort_t As[128 * 64];
    __shared__ __align__(16) ushort_t Bs[128 * 64];
    const int bn = blockIdx.x, bm = blockIdx.y;
    const int tid = threadIdx.x, w = tid >> 6, l = tid & 63;
    const int wr = w >> 1, wc = w & 1;
    const int g = l >> 4, r = l & 15;
    f32x4 acc[4][4] = {};
    // staging base: lane l covers row (l>>3) within an 8-row chunk, col (l&7)*8
    const ushort_t* Ab = A + (size_t)bm * 128 * K + (size_t)(l >> 3) * K + (l & 7) * 8;
    const ushort_t* Bb = Bw + (size_t)bn * 128 * K + (size_t)(l >> 3) * K + (l & 7) * 8;

    for (int kt = 0; kt < K; kt += 64) {
#pragma unroll
        for (int i = 0; i < 4; ++i) {
            const int chunk = i * 4 + w;                // 0..15, 8 rows each
            gld_lds16(&As[chunk * 512], Ab + (size_t)(chunk * 8) * K + kt);
            gld_lds16(&Bs[chunk * 512], Bb + (size_t)(chunk * 8) * K + kt);
        }
        asm volatile("s_waitcnt vmcnt(0)" ::: "memory");
        __syncthreads();
#pragma unroll
        for (int kk = 0; kk < 2; ++kk) {
            bf16x8 a[4], b[4];
#pragma unroll
            for (int mi = 0; mi < 4; ++mi)
                a[mi] = *(const bf16x8*)&As[(wr*64 + mi*16 + r) * 64 + kk*32 + g*8];
#pragma unroll
            for (int ni = 0; ni < 4; ++ni)
                b[ni] = *(const bf16x8*)&Bs[(wc*64 + ni*16 + r) * 64 + kk*32 + g*8];
#pragma unroll
            for (int mi = 0; mi < 4; ++mi)
#pragma unroll
                for (int ni = 0; ni < 4; ++ni)
                    acc[mi][ni] = __builtin_amdgcn_mfma_f32_16x16x32_bf16(
                        a[mi], b[ni], acc[mi][ni], 0, 0, 0);
        }
        __syncthreads();
    }
    // epilogue: C row = bm*128 + wr*64 + mi*16 + 4g + j ; col = bn*128 + wc*64 + ni*16 + r
#pragma unroll
    for (int mi = 0; mi < 4; ++mi) {
#pragma unroll
        for (int ni = 0; ni < 4; ++ni) {
            const int col = bn*128 + wc*64 + ni*16 + r;
            const float bc = bias[col];
#pragma unroll
            for (int j = 0; j < 4; ++j) {
                const int row = bm*128 + wr*64 + mi*16 + 4*g + j;
                const float v = acc[mi][ni][j] + bc;
                if (OUTF32) ((float*)Cout)[(size_t)row * N + col] = v;
                else        ((ushort_t*)Cout)[(size_t)row * N + col] = f2bf(v);
            }
        }
    }
}

// ---------------------------------------------------------------- prep q/k
// Per row (b,s): RMSNorm(q)+RoPE -> qh[B,H,S,64] (scaled by 1/8),
//                RMSNorm(k)+RoPE -> kh[B,H,S,64].
__global__ __launch_bounds__(256) void prep_qk(
    const ushort_t* __restrict__ qkvb, const float* __restrict__ cosb,
    const float* __restrict__ sinb, const float* __restrict__ gq,
    const float* __restrict__ gk, ushort_t* __restrict__ qh,
    ushort_t* __restrict__ kh)
{
    const int row = blockIdx.x;               // b*2048 + s
    const int b = row >> 11, s = row & 2047;
    const int t = threadIdx.x, w = t >> 6, l = t & 63;
    const int d0 = t * 8;
    const ushort_t* qr = qkvb + (size_t)row * 6144 + d0;
    bf16x8 qv = *(const bf16x8*)qr;
    bf16x8 kv = *(const bf16x8*)(qr + 2048);
    float qf[8], kf[8];
#pragma unroll
    for (int j = 0; j < 8; ++j) {
        qf[j] = bf2f((unsigned short)qv[j]);
        kf[j] = bf2f((unsigned short)kv[j]);
    }
    float sq = 0.f, sk = 0.f;
#pragma unroll
    for (int j = 0; j < 8; ++j) { sq += qf[j]*qf[j]; sk += kf[j]*kf[j]; }
#pragma unroll
    for (int off = 1; off < 64; off <<= 1) {
        sq += __shfl_xor(sq, off);
        sk += __shfl_xor(sk, off);
    }
    __shared__ float red[2][4];
    if (l == 0) { red[0][w] = sq; red[1][w] = sk; }
    __syncthreads();
    sq = red[0][0] + red[0][1] + red[0][2] + red[0][3];
    sk = red[1][0] + red[1][1] + red[1][2] + red[1][3];
    const float rq = rsqrtf(sq * (1.f/2048.f) + 1e-6f);
    const float rk = rsqrtf(sk * (1.f/2048.f) + 1e-6f);

    const float* cp = cosb + (size_t)row * 2048 + d0;
    const float* sp = sinb + (size_t)row * 2048 + d0;
    float4 c0 = *(const float4*)cp,       c1 = *(const float4*)(cp + 4);
    float4 s0 = *(const float4*)sp,       s1 = *(const float4*)(sp + 4);
    float4 g0 = *(const float4*)(gq + d0), g1 = *(const float4*)(gq + d0 + 4);
    float4 h0 = *(const float4*)(gk + d0), h1 = *(const float4*)(gk + d0 + 4);
    float cf[8] = {c0.x,c0.y,c0.z,c0.w,c1.x,c1.y,c1.z,c1.w};
    float sf[8] = {s0.x,s0.y,s0.z,s0.w,s1.x,s1.y,s1.z,s1.w};
    float gqa[8] = {g0.x,g0.y,g0.z,g0.w,g1.x,g1.y,g1.z,g1.w};
    float gka[8] = {h0.x,h0.y,h0.z,h0.w,h1.x,h1.y,h1.z,h1.w};

    bf16x8 qo, ko;
#pragma unroll
    for (int p = 0; p < 4; ++p) {
        const int e = 2*p, o = 2*p + 1;
        const float qe = qf[e]*rq*gqa[e], qod = qf[o]*rq*gqa[o];
        const float ke = kf[e]*rk*gka[e], kod = kf[o]*rk*gka[o];
        qo[e] = (short)f2bf((qe*cf[e] - qod*sf[e]) * 0.125f);
        qo[o] = (short)f2bf((qod*cf[o] + qe*sf[o]) * 0.125f);
        ko[e] = (short)f2bf(ke*cf[e] - kod*sf[e]);
        ko[o] = (short)f2bf(kod*cf[o] + ke*sf[o]);
    }
    const int h = d0 >> 6, dd = d0 & 63;
    const size_t oidx = (((size_t)b*32 + h) * 2048 + s) * 64 + dd;
    *(bf16x8*)(qh + oidx) = qo;
    *(bf16x8*)(kh + oidx) = ko;
}

// ---------------------------------------------------------------- v transpose
// qkvb v-region [b*2048+s][4096 + h*64 + d] -> vT[bh][d][s]
__global__ __launch_bounds__(256) void vtrans(
    const ushort_t* __restrict__ qkvb, ushort_t* __restrict__ vT)
{
    const int blk = blockIdx.x;               // bh*32 + stile
    const int bh = blk >> 5, stile = blk & 31;
    const int b = bh >> 5, h = bh & 31;
    __shared__ ushort_t tile[64][68];
    const int t = threadIdx.x;
#pragma unroll
    for (int i = 0; i < 16; ++i) {
        const int idx = i * 256 + t;
        const int sl = idx >> 6, d = idx & 63;
        tile[sl][d] = qkvb[(size_t)(b*2048 + stile*64 + sl) * 6144 + 4096 + h*64 + d];
    }
    __syncthreads();
#pragma unroll
    for (int i = 0; i < 16; ++i) {
        const int idx = i * 256 + t;
        const int d = idx >> 6, so = idx & 63;
        vT[((size_t)bh * 64 + d) * 2048 + stile*64 + so] = tile[so][d];
    }
}

// ---------------------------------------------------------------- attention
// Per block: (bh, qtile of 64 rows). 4 independent waves, 16 q-rows each.
// Swapped QK^T: st = mfma(Kfrag, Qfrag) so lane r holds a full P-row slice.
__global__ __launch_bounds__(256, 2) void attn_fwd(
    const ushort_t* __restrict__ qh, const ushort_t* __restrict__ kh,
    const ushort_t* __restrict__ vT, ushort_t* __restrict__ aout)
{
    const int blk = blockIdx.x;
    const int bh = blk >> 5, qt = blk & 31;
    const int bidx = bh >> 5, h = bh & 31;
    const int tid = threadIdx.x, w = tid >> 6, l = tid & 63;
    const int g = l >> 4, r = l & 15;
    const int q0 = qt * 64 + w * 16;
    const ushort_t* Qb = qh + ((size_t)bh * 2048 + q0) * 64;
    const ushort_t* Kb = kh + (size_t)bh * 2048 * 64;
    const ushort_t* Vb = vT + (size_t)bh * 64 * 2048;
    __shared__ __align__(16) ushort_t plds[4][16][72];   // pad 72: 144B rows
    ushort_t* prow = &plds[w][r][0];

    bf16x8 qf[2];
#pragma unroll
    for (int kk = 0; kk < 2; ++kk)
        qf[kk] = *(const bf16x8*)(Qb + (size_t)r * 64 + kk*32 + g*8);

    f32x4 o[4] = {};
    float m = -INFINITY, lsum = 0.f;

    for (int kv = 0; kv < 2048; kv += 64) {
        bf16x8 kf2[4][2], vf[2][4];
#pragma unroll
        for (int t2 = 0; t2 < 4; ++t2)
#pragma unroll
            for (int kk = 0; kk < 2; ++kk)
                kf2[t2][kk] = *(const bf16x8*)(Kb + (size_t)(kv + 16*t2 + r) * 64 + kk*32 + g*8);
#pragma unroll
        for (int ks = 0; ks < 2; ++ks)
#pragma unroll
            for (int c = 0; c < 4; ++c)
                vf[ks][c] = *(const bf16x8*)(Vb + (size_t)(16*c + r) * 2048 + kv + ks*32 + g*8);

        f32x4 st[4] = {};
#pragma unroll
        for (int t2 = 0; t2 < 4; ++t2)
#pragma unroll
            for (int kk = 0; kk < 2; ++kk)
                st[t2] = __builtin_amdgcn_mfma_f32_16x16x32_bf16(
                    kf2[t2][kk], qf[kk], st[t2], 0, 0, 0);
        // st[t2][j] = S^T[kv + 16t2 + 4g + j][q0 + r]  (scale folded into q)

        float pmax = -INFINITY;
#pragma unroll
        for (int t2 = 0; t2 < 4; ++t2)
#pragma unroll
            for (int j = 0; j < 4; ++j) pmax = fmaxf(pmax, st[t2][j]);
        pmax = fmaxf(pmax, __shfl_xor(pmax, 16));
        pmax = fmaxf(pmax, __shfl_xor(pmax, 32));
        const float mnew = fmaxf(m, pmax);
        const float scl = exp2f((m - mnew) * LOG2E);

        float rs = 0.f;
#pragma unroll
        for (int t2 = 0; t2 < 4; ++t2) {
            const float p0 = exp2f((st[t2][0] - mnew) * LOG2E);
            const float p1 = exp2f((st[t2][1] - mnew) * LOG2E);
            const float p2 = exp2f((st[t2][2] - mnew) * LOG2E);
            const float p3 = exp2f((st[t2][3] - mnew) * LOG2E);
            rs += p0 + p1 + p2 + p3;
            ushort4 pk;
            pk.x = f2bf(p0); pk.y = f2bf(p1); pk.z = f2bf(p2); pk.w = f2bf(p3);
            *(ushort4*)(prow + 16*t2 + 4*g) = pk;
        }
        rs += __shfl_xor(rs, 16);
        rs += __shfl_xor(rs, 32);
        lsum = lsum * scl + rs;
        m = mnew;

#pragma unroll
        for (int j = 0; j < 4; ++j) {
            const float sj = __shfl(scl, 4*g + j);
#pragma unroll
            for (int c = 0; c < 4; ++c) o[c][j] *= sj;
        }

        asm volatile("s_waitcnt lgkmcnt(0)" ::: "memory");
        __builtin_amdgcn_sched_barrier(0);

        bf16x8 pa[2];
#pragma unroll
        for (int ks = 0; ks < 2; ++ks)
            pa[ks] = *(const bf16x8*)(&plds[w][r][ks*32 + g*8]);
#pragma unroll
        for (int ks = 0; ks < 2; ++ks)
#pragma unroll
            for (int c = 0; c < 4; ++c)
                o[c] = __builtin_amdgcn_mfma_f32_16x16x32_bf16(
                    pa[ks], vf[ks][c], o[c], 0, 0, 0);
    }

    const float rinv = 1.f / lsum;
#pragma unroll
    for (int j = 0; j < 4; ++j) {
        const float lj = __shfl(rinv, 4*g + j);
        const int s = q0 + 4*g + j;
#pragma unroll
        for (int c = 0; c < 4; ++c)
            aout[((size_t)bidx * 2048 + s) * 2048 + h*64 + 16*c + r] =
                f2bf(o[c][j] * lj);
    }
}

// ---------------------------------------------------------------- launch
extern "C" void kernel_launch(void* const* d_in, const int* in_sizes, int n_in,
                              void* d_out, int out_size, void* d_ws, size_t ws_size,
                              hipStream_t stream) {
    const float* x    = (const float*)d_in[0];
    const float* cosb = (const float*)d_in[1];
    const float* sinb = (const float*)d_in[2];
    const float* Wq   = (const float*)d_in[3];
    const float* bq   = (const float*)d_in[4];
    const float* Wk   = (const float*)d_in[5];
    const float* bk   = (const float*)d_in[6];
    const float* Wv   = (const float*)d_in[7];
    const float* bv   = (const float*)d_in[8];
    const float* Wo   = (const float*)d_in[9];
    const float* bo   = (const float*)d_in[10];
    const float* gq   = (const float*)d_in[11];
    const float* gk   = (const float*)d_in[12];

    char* W = (char*)d_ws;
    ushort_t* xb      = (ushort_t*)(W);                  // 16,777,216 B
    ushort_t* wqkvb   = (ushort_t*)(W + 16777216);       // 25,165,824 B
    ushort_t* wob     = (ushort_t*)(W + 41943040);       //  8,388,608 B
    float*    biasqkv = (float*)   (W + 50331648);       //     24,576 B
    ushort_t* qkvb    = (ushort_t*)(W + 50356224);       // 50,331,648 B
    ushort_t* qh      = (ushort_t*)(W + 100687872);      // 16,777,216 B
    ushort_t* kh      = (ushort_t*)(W + 117465088);      // 16,777,216 B
    ushort_t* vTb     = (ushort_t*)(W + 134242304);      // 16,777,216 B
    ushort_t* attnb   = xb;  // xb dead after GEMM1; reuse for attention out

    cast_all<<<24582, 256, 0, stream>>>(x, Wq, Wk, Wv, Wo, bq, bk, bv,
                                        xb, wqkvb, wob, biasqkv);
    gemm_bt<0><<<dim3(48, 32), 256, 0, stream>>>(xb, wqkvb, biasqkv, qkvb,
                                                 4096, 6144, 2048);
    prep_qk<<<4096, 256, 0, stream>>>(qkvb, cosb, sinb, gq, gk, qh, kh);
    vtrans<<<2048, 256, 0, stream>>>(qkvb, vTb);
    attn_fwd<<<2048, 256, 0, stream>>>(qh, kh, vTb, attnb);
    gemm_bt<1><<<dim3(16, 32), 256, 0, stream>>>(attnb, wob, bo, (float*)d_out,
                                                 4096, 2048, 2048);
}

// Round 3
// 513.924 us; speedup vs baseline: 1.5995x; 1.5995x over previous
//
#include <hip/hip_runtime.h>
#include <cmath>
#include <stdint.h>

typedef unsigned short ushort_t;
typedef __attribute__((ext_vector_type(8))) short bf16x8;
typedef __attribute__((ext_vector_type(4))) float f32x4;
typedef __attribute__((ext_vector_type(16))) float f32x16;

#define LOG2E 1.4426950408889634f

__device__ __forceinline__ float bf2f(unsigned short u) {
    return __uint_as_float(((unsigned)u) << 16);
}
__device__ __forceinline__ unsigned short f2bf(float f) {
    unsigned u = __float_as_uint(f);
    u = u + 0x7fffu + ((u >> 16) & 1u);
    return (unsigned short)(u >> 16);
}
__device__ __forceinline__ unsigned cvt_pk_bf16(float lo, float hi) {
    unsigned r;
    asm("v_cvt_pk_bf16_f32 %0, %1, %2" : "=v"(r) : "v"(lo), "v"(hi));
    return r;
}
__device__ __forceinline__ void gld_lds16(void* lds, const void* g) {
    __builtin_amdgcn_global_load_lds(
        (const __attribute__((address_space(1))) unsigned int*)g,
        (__attribute__((address_space(3))) unsigned int*)lds,
        16, 0, 0);
}

// ---------------------------------------------------------------- cast kernel
__global__ __launch_bounds__(256) void cast_all(
    const float* __restrict__ x, const float* __restrict__ wq,
    const float* __restrict__ wk, const float* __restrict__ wv,
    const float* __restrict__ wo, const float* __restrict__ bq,
    const float* __restrict__ bk, const float* __restrict__ bv,
    ushort_t* __restrict__ xb, ushort_t* __restrict__ wqkvb,
    ushort_t* __restrict__ wob, float* __restrict__ biasqkv)
{
    const int X4 = 2097152;   // 8.4M / 4
    const int W4 = 1048576;   // 4.2M / 4
    int i = blockIdx.x * 256 + threadIdx.x;
    if (i < X4) {
        float4 v = ((const float4*)x)[i];
        ushort_t* d = xb + (size_t)i * 4;
        d[0]=f2bf(v.x); d[1]=f2bf(v.y); d[2]=f2bf(v.z); d[3]=f2bf(v.w);
    } else if (i < X4 + 3*W4) {
        int j = i - X4;
        const float* w; int jj;
        if (j < W4)        { w = wq; jj = j; }
        else if (j < 2*W4) { w = wk; jj = j - W4; }
        else               { w = wv; jj = j - 2*W4; }
        float4 v = ((const float4*)w)[jj];
        ushort_t* d = wqkvb + (size_t)j * 4;
        d[0]=f2bf(v.x); d[1]=f2bf(v.y); d[2]=f2bf(v.z); d[3]=f2bf(v.w);
    } else if (i < X4 + 4*W4) {
        int j = i - X4 - 3*W4;
        float4 v = ((const float4*)wo)[j];
        ushort_t* d = wob + (size_t)j * 4;
        d[0]=f2bf(v.x); d[1]=f2bf(v.y); d[2]=f2bf(v.z); d[3]=f2bf(v.w);
    } else {
        int j = i - X4 - 4*W4;           // 0..1535
        const float4* s;
        if (j < 512)       s = (const float4*)bq + j;
        else if (j < 1024) s = (const float4*)bk + (j - 512);
        else               s = (const float4*)bv + (j - 1024);
        ((float4*)biasqkv)[j] = *s;
    }
}

// ---------------------------------------------------------------- GEMM (B^T)
template<int OUTF32>
__global__ __launch_bounds__(256, 2) void gemm_bt(
    const ushort_t* __restrict__ A, const ushort_t* __restrict__ Bw,
    const float* __restrict__ bias, void* __restrict__ Cout,
    int M, int N, int K)
{
    __shared__ __align__(16) ushort_t As[128 * 64];
    __shared__ __align__(16) ushort_t Bs[128 * 64];
    const int bn = blockIdx.x, bm = blockIdx.y;
    const int tid = threadIdx.x, w = tid >> 6, l = tid & 63;
    const int wr = w >> 1, wc = w & 1;
    const int g = l >> 4, r = l & 15;
    f32x4 acc[4][4] = {};
    const ushort_t* Ab = A + (size_t)bm * 128 * K + (size_t)(l >> 3) * K + (l & 7) * 8;
    const ushort_t* Bb = Bw + (size_t)bn * 128 * K + (size_t)(l >> 3) * K + (l & 7) * 8;

    for (int kt = 0; kt < K; kt += 64) {
#pragma unroll
        for (int i = 0; i < 4; ++i) {
            const int chunk = i * 4 + w;
            gld_lds16(&As[chunk * 512], Ab + (size_t)(chunk * 8) * K + kt);
            gld_lds16(&Bs[chunk * 512], Bb + (size_t)(chunk * 8) * K + kt);
        }
        asm volatile("s_waitcnt vmcnt(0)" ::: "memory");
        __syncthreads();
#pragma unroll
        for (int kk = 0; kk < 2; ++kk) {
            bf16x8 a[4], b[4];
#pragma unroll
            for (int mi = 0; mi < 4; ++mi)
                a[mi] = *(const bf16x8*)&As[(wr*64 + mi*16 + r) * 64 + kk*32 + g*8];
#pragma unroll
            for (int ni = 0; ni < 4; ++ni)
                b[ni] = *(const bf16x8*)&Bs[(wc*64 + ni*16 + r) * 64 + kk*32 + g*8];
#pragma unroll
            for (int mi = 0; mi < 4; ++mi)
#pragma unroll
                for (int ni = 0; ni < 4; ++ni)
                    acc[mi][ni] = __builtin_amdgcn_mfma_f32_16x16x32_bf16(
                        a[mi], b[ni], acc[mi][ni], 0, 0, 0);
        }
        __syncthreads();
    }
#pragma unroll
    for (int mi = 0; mi < 4; ++mi) {
#pragma unroll
        for (int ni = 0; ni < 4; ++ni) {
            const int col = bn*128 + wc*64 + ni*16 + r;
            const float bc = bias[col];
#pragma unroll
            for (int j = 0; j < 4; ++j) {
                const int row = bm*128 + wr*64 + mi*16 + 4*g + j;
                const float v = acc[mi][ni][j] + bc;
                if (OUTF32) ((float*)Cout)[(size_t)row * N + col] = v;
                else        ((ushort_t*)Cout)[(size_t)row * N + col] = f2bf(v);
            }
        }
    }
}

// ---------------------------------------------------------------- prep q/k
// RMSNorm + RoPE; writes Q,K in 32x32x16 MFMA fragment layout:
//   frag[bh][tile32][t][lane][8]: lane=(b5*32+r5): row=tile*32+r5, d=16t+8*b5+j
// Q scaled by 0.125*log2e (fold attention scale + exp2 conversion).
__global__ __launch_bounds__(256) void prep_qk(
    const ushort_t* __restrict__ qkvb, const float* __restrict__ cosb,
    const float* __restrict__ sinb, const float* __restrict__ gq,
    const float* __restrict__ gk, ushort_t* __restrict__ qfr,
    ushort_t* __restrict__ kfr)
{
    const int row = blockIdx.x;               // b*2048 + s
    const int b = row >> 11, s = row & 2047;
    const int t = threadIdx.x, w = t >> 6, l = t & 63;
    const int d0 = t * 8;
    const ushort_t* qr = qkvb + (size_t)row * 6144 + d0;
    bf16x8 qv = *(const bf16x8*)qr;
    bf16x8 kv = *(const bf16x8*)(qr + 2048);
    float qf[8], kf[8];
#pragma unroll
    for (int j = 0; j < 8; ++j) {
        qf[j] = bf2f((unsigned short)qv[j]);
        kf[j] = bf2f((unsigned short)kv[j]);
    }
    float sq = 0.f, sk = 0.f;
#pragma unroll
    for (int j = 0; j < 8; ++j) { sq += qf[j]*qf[j]; sk += kf[j]*kf[j]; }
#pragma unroll
    for (int off = 1; off < 64; off <<= 1) {
        sq += __shfl_xor(sq, off);
        sk += __shfl_xor(sk, off);
    }
    __shared__ float red[2][4];
    if (l == 0) { red[0][w] = sq; red[1][w] = sk; }
    __syncthreads();
    sq = red[0][0] + red[0][1] + red[0][2] + red[0][3];
    sk = red[1][0] + red[1][1] + red[1][2] + red[1][3];
    const float rq = rsqrtf(sq * (1.f/2048.f) + 1e-6f);
    const float rk = rsqrtf(sk * (1.f/2048.f) + 1e-6f);

    const float* cp = cosb + (size_t)row * 2048 + d0;
    const float* sp = sinb + (size_t)row * 2048 + d0;
    float4 c0 = *(const float4*)cp,       c1 = *(const float4*)(cp + 4);
    float4 s0 = *(const float4*)sp,       s1 = *(const float4*)(sp + 4);
    float4 g0 = *(const float4*)(gq + d0), g1 = *(const float4*)(gq + d0 + 4);
    float4 h0 = *(const float4*)(gk + d0), h1 = *(const float4*)(gk + d0 + 4);
    float cf[8] = {c0.x,c0.y,c0.z,c0.w,c1.x,c1.y,c1.z,c1.w};
    float sf[8] = {s0.x,s0.y,s0.z,s0.w,s1.x,s1.y,s1.z,s1.w};
    float gqa[8] = {g0.x,g0.y,g0.z,g0.w,g1.x,g1.y,g1.z,g1.w};
    float gka[8] = {h0.x,h0.y,h0.z,h0.w,h1.x,h1.y,h1.z,h1.w};

    const float QSC = 0.125f * LOG2E;
    bf16x8 qo, ko;
#pragma unroll
    for (int p = 0; p < 4; ++p) {
        const int e = 2*p, o = 2*p + 1;
        const float qe = qf[e]*rq*gqa[e], qod = qf[o]*rq*gqa[o];
        const float ke = kf[e]*rk*gka[e], kod = kf[o]*rk*gka[o];
        qo[e] = (short)f2bf((qe*cf[e] - qod*sf[e]) * QSC);
        qo[o] = (short)f2bf((qod*cf[o] + qe*sf[o]) * QSC);
        ko[e] = (short)f2bf(ke*cf[e] - kod*sf[e]);
        ko[o] = (short)f2bf(kod*cf[o] + ke*sf[o]);
    }
    // fragment-layout address
    const int h = d0 >> 6;
    const int dh0 = d0 & 63;
    const int tf = (dh0 >> 4) & 3, b5 = (dh0 >> 3) & 1;
    const int lane = b5 * 32 + (s & 31);
    const int tile = s >> 5;
    const size_t oidx = ((((size_t)b*32 + h) * 64 + tile) * 4 + tf) * 512 + lane * 8;
    *(bf16x8*)(qfr + oidx) = qo;
    *(bf16x8*)(kfr + oidx) = ko;
}

// ---------------------------------------------------------------- V fragments
// V^T A-fragments: vf[bh][kvt64][dt][s][lane][8]:
//   lane=(b5,r5): V[kv0+16s+8*b5+j][32*dt+r5]
__global__ __launch_bounds__(256) void vfrag(
    const ushort_t* __restrict__ qkvb, ushort_t* __restrict__ vf)
{
    const int blk = blockIdx.x;               // bh*32 + kvt64
    const int bh = blk >> 5, kvt = blk & 31;
    const int b = bh >> 5, h = bh & 31;
    __shared__ ushort_t tile[64][72];
    const int tid = threadIdx.x;
#pragma unroll
    for (int it = 0; it < 2; ++it) {
        const int chunk = it * 256 + tid;     // 0..511
        const int sl = chunk >> 3, dp = (chunk & 7) * 8;
        bf16x8 v = *(const bf16x8*)&qkvb[(size_t)(b*2048 + kvt*64 + sl) * 6144 + 4096 + h*64 + dp];
        *(bf16x8*)&tile[sl][dp] = v;
    }
    __syncthreads();
#pragma unroll
    for (int it = 0; it < 2; ++it) {
        const int oc = it * 256 + tid;        // 0..511
        const int dt = oc >> 8, s = (oc >> 6) & 3, lane = oc & 63;
        const int b5 = lane >> 5, r5 = lane & 31;
        bf16x8 o;
#pragma unroll
        for (int j = 0; j < 8; ++j)
            o[j] = (short)tile[16*s + 8*b5 + j][32*dt + r5];
        *(bf16x8*)&vf[((((size_t)bh*32 + kvt)*2 + dt)*4 + s)*512 + lane*8] = o;
    }
}

// ---------------------------------------------------------------- attention
// 4 independent waves/block, 32 q-rows/wave, KV steps of 64. No LDS, no barriers.
// Swapped orientation: S^T = K·Q^T fragments, O^T = V^T·P^T; q-row is lane-local.
__global__ __launch_bounds__(256, 3) void attn_fwd(
    const ushort_t* __restrict__ qfr, const ushort_t* __restrict__ kfr,
    const ushort_t* __restrict__ vf, ushort_t* __restrict__ aout)
{
    const int bid = blockIdx.x;               // 1024 blocks
    const int xcd = bid & 7, li = bid >> 3;
    const int bh = xcd * 8 + (li >> 4);       // XCD-affine bh
    const int qtb = li & 15;
    const int tid = threadIdx.x, w = tid >> 6, l = tid & 63;
    const int b5 = l >> 5, r5 = l & 31;
    const int qt = qtb * 4 + w;

    const ushort_t* qbase = qfr + (((size_t)bh * 64 + qt) * 4) * 512 + l * 8;
    const ushort_t* kbase = kfr + ((size_t)bh * 64 * 4) * 512 + l * 8;
    const ushort_t* vbase = vf + ((size_t)bh * 32 * 8) * 512 + l * 8;

    bf16x8 q[4];
#pragma unroll
    for (int t = 0; t < 4; ++t)
        q[t] = *(const bf16x8*)(qbase + t * 512);

    f32x16 ot[2];
#pragma unroll
    for (int dt = 0; dt < 2; ++dt)
#pragma unroll
        for (int i = 0; i < 16; ++i) ot[dt][i] = 0.f;
    float m = -1e30f, lsum = 0.f;

    for (int kt = 0; kt < 32; ++kt) {
#pragma unroll
        for (int h2 = 0; h2 < 2; ++h2) {
            bf16x8 ka[4];
#pragma unroll
            for (int t = 0; t < 4; ++t)
                ka[t] = *(const bf16x8*)(kbase + ((size_t)(2*kt + h2) * 4 + t) * 512);
            bf16x8 va[2][2];                  // [sl][dt]
#pragma unroll
            for (int sl = 0; sl < 2; ++sl)
#pragma unroll
                for (int dt = 0; dt < 2; ++dt)
                    va[sl][dt] = *(const bf16x8*)(vbase + (((size_t)kt * 2 + dt) * 4 + 2*h2 + sl) * 512);

            f32x16 st = {};
#pragma unroll
            for (int t = 0; t < 4; ++t)
                st = __builtin_amdgcn_mfma_f32_32x32x16_bf16(ka[t], q[t], st, 0, 0, 0);
            // st[reg]: S^T[kv0 + 32*h2 + (reg&3)+8*(reg>>2)+4*b5][qt*32 + r5]

            float pmax = st[0];
#pragma unroll
            for (int i = 1; i < 16; ++i) pmax = fmaxf(pmax, st[i]);
            if (!__all(pmax <= m + 8.f)) {    // defer-max: rare
                float prm = __shfl_xor(pmax, 32);
                float mnew = fmaxf(m, fmaxf(pmax, prm));
                float scl = exp2f(m - mnew);
#pragma unroll
                for (int dt = 0; dt < 2; ++dt)
#pragma unroll
                    for (int i = 0; i < 16; ++i) ot[dt][i] *= scl;
                lsum *= scl;
                m = mnew;
            }
            float pe[16];
#pragma unroll
            for (int i = 0; i < 16; ++i) pe[i] = exp2f(st[i] - m);
            float a0 = pe[0] + pe[1], a1 = pe[2] + pe[3];
            float a2 = pe[4] + pe[5], a3 = pe[6] + pe[7];
            float a4 = pe[8] + pe[9], a5 = pe[10] + pe[11];
            float a6 = pe[12] + pe[13], a7 = pe[14] + pe[15];
            lsum += ((a0 + a1) + (a2 + a3)) + ((a4 + a5) + (a6 + a7));

            unsigned pk[8];                   // [blk*2+i]: kvw=32h2+8blk+4b5+2i
#pragma unroll
            for (int blk = 0; blk < 4; ++blk)
#pragma unroll
                for (int i = 0; i < 2; ++i)
                    pk[blk*2+i] = cvt_pk_bf16(pe[blk*4 + 2*i], pe[blk*4 + 2*i + 1]);

#pragma unroll
            for (int sl = 0; sl < 2; ++sl) {
                const unsigned X0 = pk[(2*sl)*2+0], X1 = pk[(2*sl)*2+1];
                const unsigned Y0 = pk[(2*sl+1)*2+0], Y1 = pk[(2*sl+1)*2+1];
                const unsigned sX0 = (unsigned)__shfl_xor((int)X0, 32);
                const unsigned sX1 = (unsigned)__shfl_xor((int)X1, 32);
                const unsigned sY0 = (unsigned)__shfl_xor((int)Y0, 32);
                const unsigned sY1 = (unsigned)__shfl_xor((int)Y1, 32);
                union { unsigned u[4]; bf16x8 v; } pb;
                pb.u[0] = b5 ? sY0 : X0;
                pb.u[1] = b5 ? sY1 : X1;
                pb.u[2] = b5 ? Y0 : sX0;
                pb.u[3] = b5 ? Y1 : sX1;
                ot[0] = __builtin_amdgcn_mfma_f32_32x32x16_bf16(va[sl][0], pb.v, ot[0], 0, 0, 0);
                ot[1] = __builtin_amdgcn_mfma_f32_32x32x16_bf16(va[sl][1], pb.v, ot[1], 0, 0, 0);
            }
        }
    }

    float prs = __shfl_xor(lsum, 32);
    const float rinv = 1.f / (lsum + prs);
    const int b = bh >> 5, h = bh & 31;
    const int sq = qt * 32 + r5;
    ushort_t* orow = aout + ((size_t)b * 2048 + sq) * 2048 + h * 64;
#pragma unroll
    for (int dt = 0; dt < 2; ++dt)
#pragma unroll
        for (int rb = 0; rb < 4; ++rb) {
            ushort4 pk4;
            pk4.x = f2bf(ot[dt][4*rb+0] * rinv);
            pk4.y = f2bf(ot[dt][4*rb+1] * rinv);
            pk4.z = f2bf(ot[dt][4*rb+2] * rinv);
            pk4.w = f2bf(ot[dt][4*rb+3] * rinv);
            *(ushort4*)(orow + 32*dt + 8*rb + 4*b5) = pk4;
        }
}

// ---------------------------------------------------------------- launch
extern "C" void kernel_launch(void* const* d_in, const int* in_sizes, int n_in,
                              void* d_out, int out_size, void* d_ws, size_t ws_size,
                              hipStream_t stream) {
    const float* x    = (const float*)d_in[0];
    const float* cosb = (const float*)d_in[1];
    const float* sinb = (const float*)d_in[2];
    const float* Wq   = (const float*)d_in[3];
    const float* bq   = (const float*)d_in[4];
    const float* Wk   = (const float*)d_in[5];
    const float* bk   = (const float*)d_in[6];
    const float* Wv   = (const float*)d_in[7];
    const float* bv   = (const float*)d_in[8];
    const float* Wo   = (const float*)d_in[9];
    const float* bo   = (const float*)d_in[10];
    const float* gq   = (const float*)d_in[11];
    const float* gk   = (const float*)d_in[12];

    char* W = (char*)d_ws;
    ushort_t* xb      = (ushort_t*)(W);                  // 16,777,216 B
    ushort_t* wqkvb   = (ushort_t*)(W + 16777216);       // 25,165,824 B
    ushort_t* wob     = (ushort_t*)(W + 41943040);       //  8,388,608 B
    float*    biasqkv = (float*)   (W + 50331648);       //     24,576 B
    ushort_t* qkvb    = (ushort_t*)(W + 50356224);       // 50,331,648 B
    ushort_t* qfb     = (ushort_t*)(W + 100687872);      // 16,777,216 B
    ushort_t* kfb     = (ushort_t*)(W + 117465088);      // 16,777,216 B
    ushort_t* vfb     = (ushort_t*)(W + 134242304);      // 16,777,216 B
    ushort_t* attnb   = xb;  // xb dead after GEMM1; reuse for attention out

    cast_all<<<24582, 256, 0, stream>>>(x, Wq, Wk, Wv, Wo, bq, bk, bv,
                                        xb, wqkvb, wob, biasqkv);
    gemm_bt<0><<<dim3(48, 32), 256, 0, stream>>>(xb, wqkvb, biasqkv, qkvb,
                                                 4096, 6144, 2048);
    prep_qk<<<4096, 256, 0, stream>>>(qkvb, cosb, sinb, gq, gk, qfb, kfb);
    vfrag<<<2048, 256, 0, stream>>>(qkvb, vfb);
    attn_fwd<<<1024, 256, 0, stream>>>(qfb, kfb, vfb, attnb);
    gemm_bt<1><<<dim3(16, 32), 256, 0, stream>>>(attnb, wob, bo, (float*)d_out,
                                                 4096, 2048, 2048);
}

// Round 8
// 507.178 us; speedup vs baseline: 1.6208x; 1.0133x over previous
//
#include <hip/hip_runtime.h>
#include <cmath>
#include <stdint.h>

typedef unsigned short ushort_t;
typedef __attribute__((ext_vector_type(8))) short bf16x8;
typedef __attribute__((ext_vector_type(4))) float f32x4;
typedef __attribute__((ext_vector_type(16))) float f32x16;

#define LOG2E 1.4426950408889634f

__device__ __forceinline__ float bf2f(unsigned short u) {
    return __uint_as_float(((unsigned)u) << 16);
}
__device__ __forceinline__ unsigned short f2bf(float f) {
    unsigned u = __float_as_uint(f);
    u = u + 0x7fffu + ((u >> 16) & 1u);
    return (unsigned short)(u >> 16);
}
__device__ __forceinline__ unsigned cvt_pk_bf16(float lo, float hi) {
    unsigned r;
    asm("v_cvt_pk_bf16_f32 %0, %1, %2" : "=v"(r) : "v"(lo), "v"(hi));
    return r;
}
__device__ __forceinline__ void gld_lds16(void* lds, const void* g) {
    __builtin_amdgcn_global_load_lds(
        (const __attribute__((address_space(1))) unsigned int*)g,
        (__attribute__((address_space(3))) unsigned int*)lds,
        16, 0, 0);
}

// ---------------------------------------------------------------- cast kernel
__global__ __launch_bounds__(256) void cast_all(
    const float* __restrict__ x, const float* __restrict__ wq,
    const float* __restrict__ wk, const float* __restrict__ wv,
    const float* __restrict__ wo, const float* __restrict__ bq,
    const float* __restrict__ bk, const float* __restrict__ bv,
    ushort_t* __restrict__ xb, ushort_t* __restrict__ wqkvb,
    ushort_t* __restrict__ wob, float* __restrict__ biasqkv)
{
    const int X4 = 2097152;   // 8.4M / 4
    const int W4 = 1048576;   // 4.2M / 4
    int i = blockIdx.x * 256 + threadIdx.x;
    if (i < X4) {
        float4 v = ((const float4*)x)[i];
        ushort_t* d = xb + (size_t)i * 4;
        d[0]=f2bf(v.x); d[1]=f2bf(v.y); d[2]=f2bf(v.z); d[3]=f2bf(v.w);
    } else if (i < X4 + 3*W4) {
        int j = i - X4;
        const float* w; int jj;
        if (j < W4)        { w = wq; jj = j; }
        else if (j < 2*W4) { w = wk; jj = j - W4; }
        else               { w = wv; jj = j - 2*W4; }
        float4 v = ((const float4*)w)[jj];
        ushort_t* d = wqkvb + (size_t)j * 4;
        d[0]=f2bf(v.x); d[1]=f2bf(v.y); d[2]=f2bf(v.z); d[3]=f2bf(v.w);
    } else if (i < X4 + 4*W4) {
        int j = i - X4 - 3*W4;
        float4 v = ((const float4*)wo)[j];
        ushort_t* d = wob + (size_t)j * 4;
        d[0]=f2bf(v.x); d[1]=f2bf(v.y); d[2]=f2bf(v.z); d[3]=f2bf(v.w);
    } else {
        int j = i - X4 - 4*W4;           // 0..1535
        const float4* s;
        if (j < 512)       s = (const float4*)bq + j;
        else if (j < 1024) s = (const float4*)bk + (j - 512);
        else               s = (const float4*)bv + (j - 1024);
        ((float4*)biasqkv)[j] = *s;
    }
}

// ---------------------------------------------------------------- GEMM (B^T)
template<int OUTF32>
__global__ __launch_bounds__(256, 2) void gemm_bt(
    const ushort_t* __restrict__ A, const ushort_t* __restrict__ Bw,
    const float* __restrict__ bias, void* __restrict__ Cout,
    int M, int N, int K)
{
    __shared__ __align__(16) ushort_t As[128 * 64];
    __shared__ __align__(16) ushort_t Bs[128 * 64];
    const int bn = blockIdx.x, bm = blockIdx.y;
    const int tid = threadIdx.x, w = tid >> 6, l = tid & 63;
    const int wr = w >> 1, wc = w & 1;
    const int g = l >> 4, r = l & 15;
    f32x4 acc[4][4] = {};
    const ushort_t* Ab = A + (size_t)bm * 128 * K + (size_t)(l >> 3) * K + (l & 7) * 8;
    const ushort_t* Bb = Bw + (size_t)bn * 128 * K + (size_t)(l >> 3) * K + (l & 7) * 8;

    for (int kt = 0; kt < K; kt += 64) {
#pragma unroll
        for (int i = 0; i < 4; ++i) {
            const int chunk = i * 4 + w;
            gld_lds16(&As[chunk * 512], Ab + (size_t)(chunk * 8) * K + kt);
            gld_lds16(&Bs[chunk * 512], Bb + (size_t)(chunk * 8) * K + kt);
        }
        asm volatile("s_waitcnt vmcnt(0)" ::: "memory");
        __syncthreads();
#pragma unroll
        for (int kk = 0; kk < 2; ++kk) {
            bf16x8 a[4], b[4];
#pragma unroll
            for (int mi = 0; mi < 4; ++mi)
                a[mi] = *(const bf16x8*)&As[(wr*64 + mi*16 + r) * 64 + kk*32 + g*8];
#pragma unroll
            for (int ni = 0; ni < 4; ++ni)
                b[ni] = *(const bf16x8*)&Bs[(wc*64 + ni*16 + r) * 64 + kk*32 + g*8];
#pragma unroll
            for (int mi = 0; mi < 4; ++mi)
#pragma unroll
                for (int ni = 0; ni < 4; ++ni)
                    acc[mi][ni] = __builtin_amdgcn_mfma_f32_16x16x32_bf16(
                        a[mi], b[ni], acc[mi][ni], 0, 0, 0);
        }
        __syncthreads();
    }
#pragma unroll
    for (int mi = 0; mi < 4; ++mi) {
#pragma unroll
        for (int ni = 0; ni < 4; ++ni) {
            const int col = bn*128 + wc*64 + ni*16 + r;
            const float bc = bias[col];
#pragma unroll
            for (int j = 0; j < 4; ++j) {
                const int row = bm*128 + wr*64 + mi*16 + 4*g + j;
                const float v = acc[mi][ni][j] + bc;
                if (OUTF32) ((float*)Cout)[(size_t)row * N + col] = v;
                else        ((ushort_t*)Cout)[(size_t)row * N + col] = f2bf(v);
            }
        }
    }
}

// ---------------------------------------------------------------- prep q/k
// RMSNorm + RoPE; writes Q,K in 32x32x16 MFMA fragment layout:
//   frag[bh][tile32][t][lane][8]: lane=(b5*32+r5): row=tile*32+r5, d=16t+8*b5+j
// Q scaled by 0.125*log2e (fold attention scale + exp2 conversion).
__global__ __launch_bounds__(256) void prep_qk(
    const ushort_t* __restrict__ qkvb, const float* __restrict__ cosb,
    const float* __restrict__ sinb, const float* __restrict__ gq,
    const float* __restrict__ gk, ushort_t* __restrict__ qfr,
    ushort_t* __restrict__ kfr)
{
    const int row = blockIdx.x;               // b*2048 + s
    const int b = row >> 11, s = row & 2047;
    const int t = threadIdx.x, w = t >> 6, l = t & 63;
    const int d0 = t * 8;
    const ushort_t* qr = qkvb + (size_t)row * 6144 + d0;
    bf16x8 qv = *(const bf16x8*)qr;
    bf16x8 kv = *(const bf16x8*)(qr + 2048);
    float qf[8], kf[8];
#pragma unroll
    for (int j = 0; j < 8; ++j) {
        qf[j] = bf2f((unsigned short)qv[j]);
        kf[j] = bf2f((unsigned short)kv[j]);
    }
    float sq = 0.f, sk = 0.f;
#pragma unroll
    for (int j = 0; j < 8; ++j) { sq += qf[j]*qf[j]; sk += kf[j]*kf[j]; }
#pragma unroll
    for (int off = 1; off < 64; off <<= 1) {
        sq += __shfl_xor(sq, off);
        sk += __shfl_xor(sk, off);
    }
    __shared__ float red[2][4];
    if (l == 0) { red[0][w] = sq; red[1][w] = sk; }
    __syncthreads();
    sq = red[0][0] + red[0][1] + red[0][2] + red[0][3];
    sk = red[1][0] + red[1][1] + red[1][2] + red[1][3];
    const float rq = rsqrtf(sq * (1.f/2048.f) + 1e-6f);
    const float rk = rsqrtf(sk * (1.f/2048.f) + 1e-6f);

    const float* cp = cosb + (size_t)row * 2048 + d0;
    const float* sp = sinb + (size_t)row * 2048 + d0;
    float4 c0 = *(const float4*)cp,       c1 = *(const float4*)(cp + 4);
    float4 s0 = *(const float4*)sp,       s1 = *(const float4*)(sp + 4);
    float4 g0 = *(const float4*)(gq + d0), g1 = *(const float4*)(gq + d0 + 4);
    float4 h0 = *(const float4*)(gk + d0), h1 = *(const float4*)(gk + d0 + 4);
    float cf[8] = {c0.x,c0.y,c0.z,c0.w,c1.x,c1.y,c1.z,c1.w};
    float sf[8] = {s0.x,s0.y,s0.z,s0.w,s1.x,s1.y,s1.z,s1.w};
    float gqa[8] = {g0.x,g0.y,g0.z,g0.w,g1.x,g1.y,g1.z,g1.w};
    float gka[8] = {h0.x,h0.y,h0.z,h0.w,h1.x,h1.y,h1.z,h1.w};

    const float QSC = 0.125f * LOG2E;
    bf16x8 qo, ko;
#pragma unroll
    for (int p = 0; p < 4; ++p) {
        const int e = 2*p, o = 2*p + 1;
        const float qe = qf[e]*rq*gqa[e], qod = qf[o]*rq*gqa[o];
        const float ke = kf[e]*rk*gka[e], kod = kf[o]*rk*gka[o];
        qo[e] = (short)f2bf((qe*cf[e] - qod*sf[e]) * QSC);
        qo[o] = (short)f2bf((qod*cf[o] + qe*sf[o]) * QSC);
        ko[e] = (short)f2bf(ke*cf[e] - kod*sf[e]);
        ko[o] = (short)f2bf(kod*cf[o] + ke*sf[o]);
    }
    // fragment-layout address
    const int h = d0 >> 6;
    const int dh0 = d0 & 63;
    const int tf = (dh0 >> 4) & 3, b5 = (dh0 >> 3) & 1;
    const int lane = b5 * 32 + (s & 31);
    const int tile = s >> 5;
    const size_t oidx = ((((size_t)b*32 + h) * 64 + tile) * 4 + tf) * 512 + lane * 8;
    *(bf16x8*)(qfr + oidx) = qo;
    *(bf16x8*)(kfr + oidx) = ko;
}

// ---------------------------------------------------------------- V fragments
// V^T A-fragments: vf[bh][kvt64][dt][s][lane][8]:
//   lane=(b5,r5): V[kv0+16s+8*b5+j][32*dt+r5]
__global__ __launch_bounds__(256) void vfrag(
    const ushort_t* __restrict__ qkvb, ushort_t* __restrict__ vf)
{
    const int blk = blockIdx.x;               // bh*32 + kvt64
    const int bh = blk >> 5, kvt = blk & 31;
    const int b = bh >> 5, h = bh & 31;
    __shared__ ushort_t tile[64][72];
    const int tid = threadIdx.x;
#pragma unroll
    for (int it = 0; it < 2; ++it) {
        const int chunk = it * 256 + tid;     // 0..511
        const int sl = chunk >> 3, dp = (chunk & 7) * 8;
        bf16x8 v = *(const bf16x8*)&qkvb[(size_t)(b*2048 + kvt*64 + sl) * 6144 + 4096 + h*64 + dp];
        *(bf16x8*)&tile[sl][dp] = v;
    }
    __syncthreads();
#pragma unroll
    for (int it = 0; it < 2; ++it) {
        const int oc = it * 256 + tid;        // 0..511
        const int dt = oc >> 8, s = (oc >> 6) & 3, lane = oc & 63;
        const int b5 = lane >> 5, r5 = lane & 31;
        bf16x8 o;
#pragma unroll
        for (int j = 0; j < 8; ++j)
            o[j] = (short)tile[16*s + 8*b5 + j][32*dt + r5];
        *(bf16x8*)&vf[((((size_t)bh*32 + kvt)*2 + dt)*4 + s)*512 + lane*8] = o;
    }
}

// ---------------------------------------------------------------- attention
// 2 waves/block, 32 q-rows/wave, KV steps of 32 (h2 halves), K dbuf prefetch.
// No LDS, no barriers, no online-max: fixed shift -16 folded into MFMA C-init;
// exp2f (libm -> hazard-safe v_exp_f32; Q pre-scaled by 0.125*log2e in prep).
// P redistribution via shfl_xor (round-3-verified lane algebra).
__global__ __launch_bounds__(128, 3) void attn_fwd(
    const ushort_t* __restrict__ qfr, const ushort_t* __restrict__ kfr,
    const ushort_t* __restrict__ vf, ushort_t* __restrict__ aout)
{
    const int bid = blockIdx.x;               // 2048 blocks
    const int xcd = bid & 7, li = bid >> 3;   // li 0..255
    const int bh = xcd * 8 + (li >> 5);       // XCD-affine bh
    const int qblk = li & 31;
    const int tid = threadIdx.x, w = tid >> 6, l = tid & 63;
    const int b5 = l >> 5, r5 = l & 31;
    const int qt = qblk * 2 + w;              // 0..63

    const ushort_t* qbase = qfr + (((size_t)bh * 64 + qt) * 4) * 512 + l * 8;
    const ushort_t* kbase = kfr + ((size_t)bh * 64 * 4) * 512 + l * 8;
    const ushort_t* vbase = vf + ((size_t)bh * 32 * 8) * 512 + l * 8;

    bf16x8 q[4];
#pragma unroll
    for (int t = 0; t < 4; ++t)
        q[t] = *(const bf16x8*)(qbase + t * 512);

    f32x16 ot[2];
#pragma unroll
    for (int dt = 0; dt < 2; ++dt)
#pragma unroll
        for (int i = 0; i < 16; ++i) ot[dt][i] = 0.f;
    float lsum = 0.f;

    auto loadk = [&](bf16x8 (&ka)[4], int idxh) {
#pragma unroll
        for (int t = 0; t < 4; ++t)
            ka[t] = *(const bf16x8*)(kbase + ((size_t)idxh * 4 + t) * 512);
    };

    // body for one 32-kv half-step (idxh = 2*kt + h2)
    auto body = [&](const bf16x8 (&ka)[4], int idxh) {
        bf16x8 va[2][2];                      // [sl][dt]
#pragma unroll
        for (int sl = 0; sl < 2; ++sl)
#pragma unroll
            for (int dt = 0; dt < 2; ++dt)
                va[sl][dt] = *(const bf16x8*)(vbase +
                    (((size_t)(idxh >> 1) * 2 + dt) * 4 + 2 * (idxh & 1) + sl) * 512);

        f32x16 st;
#pragma unroll
        for (int i = 0; i < 16; ++i) st[i] = -16.f;   // fixed softmax shift
#pragma unroll
        for (int t = 0; t < 4; ++t)
            st = __builtin_amdgcn_mfma_f32_32x32x16_bf16(ka[t], q[t], st, 0, 0, 0);
        // st[reg]: S^T*log2e - 16 at [kv0 + (reg&3)+8*(reg>>2)+4*b5][qt*32 + r5]

        unsigned pk[8];
        float ls0 = 0.f, ls1 = 0.f;
#pragma unroll
        for (int p = 0; p < 8; ++p) {
            const float lo = exp2f(st[2*p]);
            const float hi = exp2f(st[2*p+1]);
            if (p & 1) ls1 += lo + hi; else ls0 += lo + hi;
            pk[p] = cvt_pk_bf16(lo, hi);
        }
        lsum += ls0 + ls1;

#pragma unroll
        for (int sl = 0; sl < 2; ++sl) {
            const unsigned X0 = pk[4*sl+0], X1 = pk[4*sl+1];
            const unsigned Y0 = pk[4*sl+2], Y1 = pk[4*sl+3];
            const unsigned sX0 = (unsigned)__shfl_xor((int)X0, 32);
            const unsigned sX1 = (unsigned)__shfl_xor((int)X1, 32);
            const unsigned sY0 = (unsigned)__shfl_xor((int)Y0, 32);
            const unsigned sY1 = (unsigned)__shfl_xor((int)Y1, 32);
            union { unsigned u[4]; bf16x8 v; } pb;
            pb.u[0] = b5 ? sY0 : X0;
            pb.u[1] = b5 ? sY1 : X1;
            pb.u[2] = b5 ? Y0 : sX0;
            pb.u[3] = b5 ? Y1 : sX1;
            ot[0] = __builtin_amdgcn_mfma_f32_32x32x16_bf16(va[sl][0], pb.v, ot[0], 0, 0, 0);
            ot[1] = __builtin_amdgcn_mfma_f32_32x32x16_bf16(va[sl][1], pb.v, ot[1], 0, 0, 0);
        }
    };

    bf16x8 kaA[4], kaB[4];
    loadk(kaA, 0);
    for (int kt = 0; kt < 32; ++kt) {
        loadk(kaB, 2*kt + 1);
        body(kaA, 2*kt);
        const int nx = (kt == 31) ? 0 : (2*kt + 2);
        loadk(kaA, nx);
        body(kaB, 2*kt + 1);
    }

    const float prs = __shfl_xor(lsum, 32);
    const float rinv = 1.f / (lsum + prs);
    const int b = bh >> 5, h = bh & 31;
    const int sq = qt * 32 + r5;
    ushort_t* orow = aout + ((size_t)b * 2048 + sq) * 2048 + h * 64;
#pragma unroll
    for (int dt = 0; dt < 2; ++dt)
#pragma unroll
        for (int rb = 0; rb < 4; ++rb) {
            ushort4 pk4;
            pk4.x = f2bf(ot[dt][4*rb+0] * rinv);
            pk4.y = f2bf(ot[dt][4*rb+1] * rinv);
            pk4.z = f2bf(ot[dt][4*rb+2] * rinv);
            pk4.w = f2bf(ot[dt][4*rb+3] * rinv);
            *(ushort4*)(orow + 32*dt + 8*rb + 4*b5) = pk4;
        }
}

// ---------------------------------------------------------------- launch
extern "C" void kernel_launch(void* const* d_in, const int* in_sizes, int n_in,
                              void* d_out, int out_size, void* d_ws, size_t ws_size,
                              hipStream_t stream) {
    const float* x    = (const float*)d_in[0];
    const float* cosb = (const float*)d_in[1];
    const float* sinb = (const float*)d_in[2];
    const float* Wq   = (const float*)d_in[3];
    const float* bq   = (const float*)d_in[4];
    const float* Wk   = (const float*)d_in[5];
    const float* bk   = (const float*)d_in[6];
    const float* Wv   = (const float*)d_in[7];
    const float* bv   = (const float*)d_in[8];
    const float* Wo   = (const float*)d_in[9];
    const float* bo   = (const float*)d_in[10];
    const float* gq   = (const float*)d_in[11];
    const float* gk   = (const float*)d_in[12];

    char* W = (char*)d_ws;
    ushort_t* xb      = (ushort_t*)(W);                  // 16,777,216 B
    ushort_t* wqkvb   = (ushort_t*)(W + 16777216);       // 25,165,824 B
    ushort_t* wob     = (ushort_t*)(W + 41943040);       //  8,388,608 B
    float*    biasqkv = (float*)   (W + 50331648);       //     24,576 B
    ushort_t* qkvb    = (ushort_t*)(W + 50356224);       // 50,331,648 B
    ushort_t* qfb     = (ushort_t*)(W + 100687872);      // 16,777,216 B
    ushort_t* kfb     = (ushort_t*)(W + 117465088);      // 16,777,216 B
    ushort_t* vfb     = (ushort_t*)(W + 134242304);      // 16,777,216 B
    ushort_t* attnb   = xb;  // xb dead after GEMM1; reuse for attention out

    cast_all<<<24582, 256, 0, stream>>>(x, Wq, Wk, Wv, Wo, bq, bk, bv,
                                        xb, wqkvb, wob, biasqkv);
    gemm_bt<0><<<dim3(48, 32), 256, 0, stream>>>(xb, wqkvb, biasqkv, qkvb,
                                                 4096, 6144, 2048);
    prep_qk<<<4096, 256, 0, stream>>>(qkvb, cosb, sinb, gq, gk, qfb, kfb);
    vfrag<<<2048, 256, 0, stream>>>(qkvb, vfb);
    attn_fwd<<<2048, 128, 0, stream>>>(qfb, kfb, vfb, attnb);
    gemm_bt<1><<<dim3(16, 32), 256, 0, stream>>>(attnb, wob, bo, (float*)d_out,
                                                 4096, 2048, 2048);
}